// Round 1
// baseline (622.511 us; speedup 1.0000x reference)
//
#include <hip/hip_runtime.h>

// Grouped conv 3x3 SAME, NHWC fp32.
// x: [16,56,56,256], kernels: [8,3,3,32,64], bias: [512] -> out: [16,56,56,512]
#define NG 8
#define PC 32    // in-channels per group
#define FC 64    // out-channels per group
#define HH 56
#define WW 56
#define CIN 256
#define COUT 512

__global__ __launch_bounds__(256, 2)
void groupconv_f32_kernel(const float* __restrict__ x,
                          const float* __restrict__ krn,
                          const float* __restrict__ bias,
                          float* __restrict__ out) {
    const int b  = blockIdx.x;
    const int g  = b % NG;
    const int h  = (b / NG) % HH;
    const int n  = b / (NG * HH);
    const int tid = threadIdx.x;
    const int f   = tid & 63;        // lane = output filter within group
    const int wq  = tid >> 6;        // wave id: which quarter of the row
    const int wbase = wq * 14;       // 56 = 4 * 14

    float acc[14];
#pragma unroll
    for (int i = 0; i < 14; ++i) acc[i] = 0.f;

    const float* kg = krn + (size_t)g * (3 * 3 * PC * FC);

    for (int kh = 0; kh < 3; ++kh) {
        const int hin = h + kh - 1;
        if (hin < 0 || hin >= HH) continue;   // zero-pad row: contributes nothing
        const float* xrow = x + (((size_t)n * HH + hin) * WW) * CIN + g * PC;

        for (int pq = 0; pq < 8; ++pq) {      // 32 channels as 8 x float4
            // Batch-load 16 x-vectors covering w_in = wbase-1 .. wbase+14.
            // All 64 lanes use the same address -> wave broadcast.
            float4 xv[16];
#pragma unroll
            for (int t = 0; t < 16; ++t) {
                const int win = wbase + t - 1;
                if (win >= 0 && win < WW) {
                    xv[t] = *reinterpret_cast<const float4*>(
                        xrow + (size_t)win * CIN + pq * 4);
                } else {
                    xv[t] = make_float4(0.f, 0.f, 0.f, 0.f);
                }
            }
#pragma unroll
            for (int kw = 0; kw < 3; ++kw) {
                // weights for (g, kh, kw, p=4*pq..4*pq+3, f=lane); coalesced over f
                const float* kp = kg + ((kh * 3 + kw) * PC + pq * 4) * FC + f;
                const float w0 = kp[0 * FC];
                const float w1 = kp[1 * FC];
                const float w2 = kp[2 * FC];
                const float w3 = kp[3 * FC];
#pragma unroll
                for (int i = 0; i < 14; ++i) {
                    const float4 xt = xv[i + kw];  // out w = wbase+i uses w_in = wbase+i+kw-1
                    acc[i] = fmaf(xt.x, w0, acc[i]);
                    acc[i] = fmaf(xt.y, w1, acc[i]);
                    acc[i] = fmaf(xt.z, w2, acc[i]);
                    acc[i] = fmaf(xt.w, w3, acc[i]);
                }
            }
        }
    }

    const float bv = bias[g * FC + f];
    float* orow = out + (((size_t)n * HH + h) * WW + wbase) * COUT + g * FC + f;
#pragma unroll
    for (int i = 0; i < 14; ++i) {
        orow[(size_t)i * COUT] = acc[i] + bv;
    }
}

extern "C" void kernel_launch(void* const* d_in, const int* in_sizes, int n_in,
                              void* d_out, int out_size, void* d_ws, size_t ws_size,
                              hipStream_t stream) {
    const float* x    = (const float*)d_in[0];
    const float* krn  = (const float*)d_in[1];
    const float* bias = (const float*)d_in[2];
    float* out = (float*)d_out;

    const int blocks = 16 * HH * NG;  // (n, h, g) per block
    groupconv_f32_kernel<<<blocks, 256, 0, stream>>>(x, krn, bias, out);
}

// Round 2
// 114.950 us; speedup vs baseline: 5.4155x; 5.4155x over previous
//
#include <hip/hip_runtime.h>

// Grouped conv 3x3 SAME, NHWC fp32 -> bf16 MFMA implicit GEMM.
// x: [16,56,56,256] f32, kernels: [8,3,3,32,64] f32, bias: [512] f32
// out: [16,56,56,512] f32
#define NG 8
#define PC 32
#define FC 64
#define HH 56
#define WW 56
#define CIN 256
#define COUT 512
#define NB 16

typedef __bf16 bf16x8 __attribute__((ext_vector_type(8)));
typedef float f32x4 __attribute__((ext_vector_type(4)));

// ---------------- conversion kernels ----------------

__global__ void cvt_x_kernel(const float* __restrict__ in,
                             __bf16* __restrict__ outb, int n8) {
    int i = blockIdx.x * blockDim.x + threadIdx.x;
    const int stride = gridDim.x * blockDim.x;
    for (; i < n8; i += stride) {
        const float4* p = reinterpret_cast<const float4*>(in + (size_t)i * 8);
        float4 a = p[0], b = p[1];
        bf16x8 o;
        o[0] = (__bf16)a.x; o[1] = (__bf16)a.y; o[2] = (__bf16)a.z; o[3] = (__bf16)a.w;
        o[4] = (__bf16)b.x; o[5] = (__bf16)b.y; o[6] = (__bf16)b.z; o[7] = (__bf16)b.w;
        *reinterpret_cast<bf16x8*>(outb + (size_t)i * 8) = o;
    }
}

// kernels [g][kh][kw][p][f] f32 -> [g][tap][f][p] bf16 (B^T layout per tap)
__global__ void cvt_w_kernel(const float* __restrict__ in,
                             __bf16* __restrict__ outb) {
    int id = blockIdx.x * blockDim.x + threadIdx.x;  // 8*9*64*32 = 147456
    if (id >= NG * 9 * FC * PC) return;
    const int p = id & (PC - 1);
    int rest = id >> 5;
    const int f = rest & (FC - 1);
    rest >>= 6;
    const int t = rest % 9;
    const int g = rest / 9;
    const float v = in[(((size_t)(g * 9 + t)) * PC + p) * FC + f];
    outb[id] = (__bf16)v;
}

// ---------------- main MFMA kernel ----------------

__global__ __launch_bounds__(256)
void groupconv_mfma_kernel(const __bf16* __restrict__ xb,
                           const __bf16* __restrict__ wb,
                           const float* __restrict__ bias,
                           float* __restrict__ out) {
    const int b = blockIdx.x;
    const int g = b % NG;
    const int h = (b / NG) % HH;
    const int n = b / (NG * HH);

    const int wq   = threadIdx.x >> 6;   // wave id -> M-tile
    const int lane = threadIdx.x & 63;
    const int lo   = lane & 15;
    const int hi   = lane >> 4;

    const int wbase = wq * 16;
    const int w_m   = wbase + lo;        // output w row this lane loads A for
    const int p0    = hi * 8;            // 8 contiguous channels per lane

    f32x4 acc[4];
#pragma unroll
    for (int nt = 0; nt < 4; ++nt) acc[nt] = (f32x4)0.f;

    const __bf16* xg = xb + ((size_t)n * HH * WW) * CIN + g * PC + p0;
    const __bf16* wg = wb + ((size_t)g * 9 * FC) * PC + p0;

    for (int kh = 0; kh < 3; ++kh) {
        const int hin = h + kh - 1;
        if ((unsigned)hin >= HH) continue;
        const __bf16* xrow = xg + (size_t)hin * WW * CIN;
#pragma unroll
        for (int kw = 0; kw < 3; ++kw) {
            const int win = w_m + kw - 1;
            bf16x8 a = (bf16x8)(__bf16)0.f;
            if ((unsigned)win < WW)
                a = *reinterpret_cast<const bf16x8*>(xrow + (size_t)win * CIN);
            const int tap = kh * 3 + kw;
            const __bf16* wt = wg + (size_t)tap * FC * PC;
#pragma unroll
            for (int nt = 0; nt < 4; ++nt) {
                bf16x8 bfrag = *reinterpret_cast<const bf16x8*>(wt + (nt * 16 + lo) * PC);
                acc[nt] = __builtin_amdgcn_mfma_f32_16x16x32_bf16(a, bfrag, acc[nt], 0, 0, 0);
            }
        }
    }

    // C/D: col = lane&15 (filter), row = hi*4 + r (w position)
    const int wrow0 = wbase + hi * 4;
    float* obase = out + (((size_t)n * HH + h) * WW) * COUT + g * FC + lo;
#pragma unroll
    for (int nt = 0; nt < 4; ++nt) {
        const float bv = bias[g * FC + nt * 16 + lo];
#pragma unroll
        for (int r = 0; r < 4; ++r) {
            const int w = wrow0 + r;
            if (w < WW) obase[(size_t)w * COUT + nt * 16] = acc[nt][r] + bv;
        }
    }
}

// ---------------- fallback fp32 kernel (R0, used if ws too small) ----------------

__global__ __launch_bounds__(256, 2)
void groupconv_f32_kernel(const float* __restrict__ x,
                          const float* __restrict__ krn,
                          const float* __restrict__ bias,
                          float* __restrict__ out) {
    const int b  = blockIdx.x;
    const int g  = b % NG;
    const int h  = (b / NG) % HH;
    const int n  = b / (NG * HH);
    const int tid = threadIdx.x;
    const int f   = tid & 63;
    const int wq  = tid >> 6;
    const int wbase = wq * 14;

    float acc[14];
#pragma unroll
    for (int i = 0; i < 14; ++i) acc[i] = 0.f;

    const float* kg = krn + (size_t)g * (3 * 3 * PC * FC);

    for (int kh = 0; kh < 3; ++kh) {
        const int hin = h + kh - 1;
        if (hin < 0 || hin >= HH) continue;
        const float* xrow = x + (((size_t)n * HH + hin) * WW) * CIN + g * PC;
        for (int pq = 0; pq < 8; ++pq) {
            float4 xv[16];
#pragma unroll
            for (int t = 0; t < 16; ++t) {
                const int win = wbase + t - 1;
                if (win >= 0 && win < WW) {
                    xv[t] = *reinterpret_cast<const float4*>(
                        xrow + (size_t)win * CIN + pq * 4);
                } else {
                    xv[t] = make_float4(0.f, 0.f, 0.f, 0.f);
                }
            }
#pragma unroll
            for (int kw = 0; kw < 3; ++kw) {
                const float* kp = kg + ((kh * 3 + kw) * PC + pq * 4) * FC + f;
                const float w0 = kp[0 * FC];
                const float w1 = kp[1 * FC];
                const float w2 = kp[2 * FC];
                const float w3 = kp[3 * FC];
#pragma unroll
                for (int i = 0; i < 14; ++i) {
                    const float4 xt = xv[i + kw];
                    acc[i] = fmaf(xt.x, w0, acc[i]);
                    acc[i] = fmaf(xt.y, w1, acc[i]);
                    acc[i] = fmaf(xt.z, w2, acc[i]);
                    acc[i] = fmaf(xt.w, w3, acc[i]);
                }
            }
        }
    }

    const float bv = bias[g * FC + f];
    float* orow = out + (((size_t)n * HH + h) * WW + wbase) * COUT + g * FC + f;
#pragma unroll
    for (int i = 0; i < 14; ++i) {
        orow[(size_t)i * COUT] = acc[i] + bv;
    }
}

// ---------------- launcher ----------------

extern "C" void kernel_launch(void* const* d_in, const int* in_sizes, int n_in,
                              void* d_out, int out_size, void* d_ws, size_t ws_size,
                              hipStream_t stream) {
    const float* x    = (const float*)d_in[0];
    const float* krn  = (const float*)d_in[1];
    const float* bias = (const float*)d_in[2];
    float* out = (float*)d_out;

    const size_t x_elems = (size_t)NB * HH * WW * CIN;           // 12,845,056
    const size_t w_elems = (size_t)NG * 9 * FC * PC;             // 147,456
    const size_t need = (x_elems + w_elems) * sizeof(__bf16);    // ~26 MB

    if (ws_size < need) {
        const int blocks = NB * HH * NG;
        groupconv_f32_kernel<<<blocks, 256, 0, stream>>>(x, krn, bias, out);
        return;
    }

    __bf16* xb = (__bf16*)d_ws;
    __bf16* wb = xb + x_elems;

    const int n8 = (int)(x_elems / 8);                           // 1,605,632
    cvt_x_kernel<<<2048, 256, 0, stream>>>(x, xb, n8);
    cvt_w_kernel<<<(int)((w_elems + 255) / 256), 256, 0, stream>>>(krn, wb);

    const int blocks = NB * HH * NG;                             // 7168
    groupconv_mfma_kernel<<<blocks, 256, 0, stream>>>(xb, wb, bias, out);
}

// Round 3
// 105.268 us; speedup vs baseline: 5.9136x; 1.0920x over previous
//
#include <hip/hip_runtime.h>

// Grouped conv 3x3 SAME, NHWC fp32, bf16-MFMA weight-stationary h-walk.
// x: [16,56,56,256] f32, kernels: [8,3,3,32,64] f32, bias: [512] -> out [16,56,56,512] f32
#define NG 8
#define PC 32
#define FC 64
#define HH 56
#define WW 56
#define CIN 256
#define COUT 512
#define NB 16
#define HCH 14   // h rows walked per block

typedef __bf16 bf16x8 __attribute__((ext_vector_type(8)));
typedef float f32x4 __attribute__((ext_vector_type(4)));

// kernels [g][kh][kw][p][f] f32 -> [g][tap][f][p] bf16 (B^T per tap)
__global__ void cvt_w_kernel(const float* __restrict__ in,
                             __bf16* __restrict__ outb) {
    int id = blockIdx.x * blockDim.x + threadIdx.x;
    if (id >= NG * 9 * FC * PC) return;
    const int p = id & (PC - 1);
    int rest = id >> 5;
    const int f = rest & (FC - 1);
    rest >>= 6;
    const int t = rest % 9;
    const int g = rest / 9;
    outb[id] = (__bf16)in[(((size_t)(g * 9 + t)) * PC + p) * FC + f];
}

static __device__ __forceinline__ bf16x8 cvt8(f32x4 a, f32x4 b) {
    bf16x8 r;
    r[0] = (__bf16)a[0]; r[1] = (__bf16)a[1]; r[2] = (__bf16)a[2]; r[3] = (__bf16)a[3];
    r[4] = (__bf16)b[0]; r[5] = (__bf16)b[1]; r[6] = (__bf16)b[2]; r[7] = (__bf16)b[3];
    return r;
}

// load 8 channels (f32) of row r at w=wi, predicated; zeros when invalid
static __device__ __forceinline__ void loadf(const float* __restrict__ xg,
                                             int r, int wi, bool vw,
                                             f32x4& u0, f32x4& u1) {
    const bool v = vw && ((unsigned)r < HH);
    if (v) {
        const float* p = xg + ((size_t)r * WW + wi) * CIN;
        u0 = *reinterpret_cast<const f32x4*>(p);
        u1 = *reinterpret_cast<const f32x4*>(p + 4);
    } else {
        u0 = (f32x4)0.f;
        u1 = (f32x4)0.f;
    }
}

__global__ __launch_bounds__(256)
void groupconv_ws_kernel(const float* __restrict__ x,
                         const __bf16* __restrict__ wb,
                         const float* __restrict__ bias,
                         float* __restrict__ out) {
    const int b  = blockIdx.x;
    const int wt = b & 3;          // w tile (16-wide; tile 3 ragged: w 48..55)
    const int hc = (b >> 2) & 3;   // h chunk (14 rows)
    const int g  = (b >> 4) & 7;
    const int n  = b >> 7;

    const int wave = threadIdx.x >> 6;  // N-tile: filters [wave*16, wave*16+16)
    const int lane = threadIdx.x & 63;
    const int lo = lane & 15;
    const int hi = lane >> 4;
    const int p0 = hi * 8;
    const int w_m = wt * 16 + lo;       // M row this lane supplies A for
    const int h0 = hc * HCH;

    // ---- stationary B fragments (9 taps) ----
    bf16x8 bfr[9];
    const __bf16* wgp = wb + (((size_t)g * 9) * FC + (wave * 16 + lo)) * PC + p0;
#pragma unroll
    for (int t = 0; t < 9; ++t)
        bfr[t] = *reinterpret_cast<const bf16x8*>(wgp + (size_t)t * FC * PC);

    const float* xg = x + ((size_t)n * HH * WW) * CIN + g * PC + p0;

    bool vw[3];
    int wi[3];
#pragma unroll
    for (int kw = 0; kw < 3; ++kw) {
        wi[kw] = w_m + kw - 1;
        vw[kw] = (w_m < WW) && ((unsigned)wi[kw] < WW);
    }

    // ---- prologue: window = rows h0-1, h0, h0+1 ----
    bf16x8 aw[3][3];
#pragma unroll
    for (int rr = 0; rr < 3; ++rr) {
        const int r = h0 - 1 + rr;
#pragma unroll
        for (int kw = 0; kw < 3; ++kw) {
            f32x4 u0, u1;
            loadf(xg, r, wi[kw], vw[kw], u0, u1);
            aw[rr][kw] = cvt8(u0, u1);
        }
    }
    // prefetch row h0+2
    f32x4 pf[3][2];
#pragma unroll
    for (int kw = 0; kw < 3; ++kw)
        loadf(xg, h0 + 2, wi[kw], vw[kw], pf[kw][0], pf[kw][1]);

    const float bv = bias[g * FC + wave * 16 + lo];
    float* obase = out + ((size_t)n * HH * WW) * COUT + g * FC + wave * 16 + lo;
    const int wrow0 = wt * 16 + hi * 4;

    for (int i = 0; i < HCH; ++i) {
        const int h = h0 + i;

        f32x4 acc0 = (f32x4)0.f, acc1 = (f32x4)0.f;
#pragma unroll
        for (int kh = 0; kh < 3; ++kh) {
#pragma unroll
            for (int kw = 0; kw < 3; ++kw) {
                const int t = kh * 3 + kw;
                if (t & 1)
                    acc1 = __builtin_amdgcn_mfma_f32_16x16x32_bf16(aw[kh][kw], bfr[t], acc1, 0, 0, 0);
                else
                    acc0 = __builtin_amdgcn_mfma_f32_16x16x32_bf16(aw[kh][kw], bfr[t], acc0, 0, 0, 0);
            }
        }

        // store row h  (C/D: col=lo=filter, row=hi*4+r=w)
        const f32x4 acc = acc0 + acc1;
        float* orow = obase + ((size_t)h * WW) * COUT;
#pragma unroll
        for (int r = 0; r < 4; ++r) {
            const int w = wrow0 + r;
            if (w < WW) orow[(size_t)w * COUT] = acc[r] + bv;
        }

        // shift window down one row, consume prefetch
#pragma unroll
        for (int kw = 0; kw < 3; ++kw) {
            aw[0][kw] = aw[1][kw];
            aw[1][kw] = aw[2][kw];
            aw[2][kw] = cvt8(pf[kw][0], pf[kw][1]);
        }
        // issue prefetch for row h+3 (skip on last iter)
        const bool more = (i + 1 < HCH);
#pragma unroll
        for (int kw = 0; kw < 3; ++kw)
            loadf(xg, h + 3, wi[kw], vw[kw] && more, pf[kw][0], pf[kw][1]);
    }
}

// ---------------- fallback fp32 kernel ----------------
__global__ __launch_bounds__(256, 2)
void groupconv_f32_kernel(const float* __restrict__ x,
                          const float* __restrict__ krn,
                          const float* __restrict__ bias,
                          float* __restrict__ out) {
    const int b  = blockIdx.x;
    const int g  = b % NG;
    const int h  = (b / NG) % HH;
    const int n  = b / (NG * HH);
    const int tid = threadIdx.x;
    const int f   = tid & 63;
    const int wq  = tid >> 6;
    const int wbase = wq * 14;

    float acc[14];
#pragma unroll
    for (int i = 0; i < 14; ++i) acc[i] = 0.f;

    const float* kg = krn + (size_t)g * (9 * PC * FC);

    for (int kh = 0; kh < 3; ++kh) {
        const int hin = h + kh - 1;
        if (hin < 0 || hin >= HH) continue;
        const float* xrow = x + (((size_t)n * HH + hin) * WW) * CIN + g * PC;
        for (int pq = 0; pq < 8; ++pq) {
            float4 xv[16];
#pragma unroll
            for (int t = 0; t < 16; ++t) {
                const int win = wbase + t - 1;
                if (win >= 0 && win < WW)
                    xv[t] = *reinterpret_cast<const float4*>(xrow + (size_t)win * CIN + pq * 4);
                else
                    xv[t] = make_float4(0.f, 0.f, 0.f, 0.f);
            }
#pragma unroll
            for (int kw = 0; kw < 3; ++kw) {
                const float* kp = kg + ((kh * 3 + kw) * PC + pq * 4) * FC + f;
                const float w0 = kp[0 * FC], w1 = kp[1 * FC], w2 = kp[2 * FC], w3 = kp[3 * FC];
#pragma unroll
                for (int i = 0; i < 14; ++i) {
                    const float4 xt = xv[i + kw];
                    acc[i] = fmaf(xt.x, w0, acc[i]);
                    acc[i] = fmaf(xt.y, w1, acc[i]);
                    acc[i] = fmaf(xt.z, w2, acc[i]);
                    acc[i] = fmaf(xt.w, w3, acc[i]);
                }
            }
        }
    }

    const float bv = bias[g * FC + f];
    float* orow = out + (((size_t)n * HH + h) * WW + wbase) * COUT + g * FC + f;
#pragma unroll
    for (int i = 0; i < 14; ++i) orow[(size_t)i * COUT] = acc[i] + bv;
}

// ---------------- launcher ----------------
extern "C" void kernel_launch(void* const* d_in, const int* in_sizes, int n_in,
                              void* d_out, int out_size, void* d_ws, size_t ws_size,
                              hipStream_t stream) {
    const float* x    = (const float*)d_in[0];
    const float* krn  = (const float*)d_in[1];
    const float* bias = (const float*)d_in[2];
    float* out = (float*)d_out;

    const size_t w_elems = (size_t)NG * 9 * FC * PC;          // 147456
    if (ws_size < w_elems * sizeof(__bf16)) {
        groupconv_f32_kernel<<<NB * HH * NG, 256, 0, stream>>>(x, krn, bias, out);
        return;
    }

    __bf16* wbuf = (__bf16*)d_ws;
    cvt_w_kernel<<<(int)((w_elems + 255) / 256), 256, 0, stream>>>(krn, wbuf);

    const int blocks = NB * NG * 4 * 4;                        // 2048
    groupconv_ws_kernel<<<blocks, 256, 0, stream>>>(x, wbuf, bias, out);
}

// Round 5
// 103.428 us; speedup vs baseline: 6.0188x; 1.0178x over previous
//
#include <hip/hip_runtime.h>

// Grouped conv 3x3 SAME, NHWC fp32, bf16-MFMA weight-stationary h-walk v2.
// vs R2: loads-before-stores, depth-2 prefetch, full unroll,
// swapped-operand MFMA (C^T) -> one 16B store/lane, NT stores.
// vs R3: nontemporal store uses ext_vector f32x4* (float4* rejected by builtin).
#define NG 8
#define PC 32
#define FC 64
#define HH 56
#define WW 56
#define CIN 256
#define COUT 512
#define NB 16
#define HCH 14

typedef __bf16 bf16x8 __attribute__((ext_vector_type(8)));
typedef float f32x4 __attribute__((ext_vector_type(4)));

// kernels [g][kh][kw][p][f] f32 -> [g][tap][f][p] bf16
__global__ void cvt_w_kernel(const float* __restrict__ in,
                             __bf16* __restrict__ outb) {
    int id = blockIdx.x * blockDim.x + threadIdx.x;
    if (id >= NG * 9 * FC * PC) return;
    const int p = id & (PC - 1);
    int rest = id >> 5;
    const int f = rest & (FC - 1);
    rest >>= 6;
    const int t = rest % 9;
    const int g = rest / 9;
    outb[id] = (__bf16)in[(((size_t)(g * 9 + t)) * PC + p) * FC + f];
}

static __device__ __forceinline__ bf16x8 cvt8(f32x4 a, f32x4 b) {
    bf16x8 r;
    r[0] = (__bf16)a[0]; r[1] = (__bf16)a[1]; r[2] = (__bf16)a[2]; r[3] = (__bf16)a[3];
    r[4] = (__bf16)b[0]; r[5] = (__bf16)b[1]; r[6] = (__bf16)b[2]; r[7] = (__bf16)b[3];
    return r;
}

static __device__ __forceinline__ void loadf(const float* __restrict__ xg,
                                             int r, int wi, bool vw,
                                             f32x4& u0, f32x4& u1) {
    const bool v = vw && ((unsigned)r < HH);
    if (v) {
        const float* p = xg + ((size_t)r * WW + wi) * CIN;
        u0 = *reinterpret_cast<const f32x4*>(p);
        u1 = *reinterpret_cast<const f32x4*>(p + 4);
    } else {
        u0 = (f32x4)0.f;
        u1 = (f32x4)0.f;
    }
}

__global__ __launch_bounds__(256)
void groupconv_ws2_kernel(const float* __restrict__ x,
                          const __bf16* __restrict__ wb,
                          const float* __restrict__ bias,
                          float* __restrict__ out) {
    const int b  = blockIdx.x;
    const int wt = b & 3;
    const int hc = (b >> 2) & 3;
    const int g  = (b >> 4) & 7;
    const int n  = b >> 7;

    const int wave = threadIdx.x >> 6;   // filter sub-tile [wave*16, wave*16+16)
    const int lane = threadIdx.x & 63;
    const int lo = lane & 15;
    const int hi = lane >> 4;
    const int p0 = hi * 8;
    const int w_m = wt * 16 + lo;        // w position (B-operand col / store col)
    const int h0 = hc * HCH;

    // stationary weight frags (A-operand: M=16 filters, row=lo, k=p0+0..7)
    bf16x8 bfr[9];
    const __bf16* wgp = wb + (((size_t)g * 9) * FC + (wave * 16 + lo)) * PC + p0;
#pragma unroll
    for (int t = 0; t < 9; ++t)
        bfr[t] = *reinterpret_cast<const bf16x8*>(wgp + (size_t)t * FC * PC);

    const float* xg = x + ((size_t)n * HH * WW) * CIN + g * PC + p0;

    bool vw[3];
    int wi[3];
#pragma unroll
    for (int kw = 0; kw < 3; ++kw) {
        wi[kw] = w_m + kw - 1;
        vw[kw] = (w_m < WW) && ((unsigned)wi[kw] < WW);
    }

    // prologue: window rows h0-1..h0+1; prefetch rows h0+2, h0+3
    f32x4 wl[3][3][2];
#pragma unroll
    for (int rr = 0; rr < 3; ++rr)
#pragma unroll
        for (int kw = 0; kw < 3; ++kw)
            loadf(xg, h0 - 1 + rr, wi[kw], vw[kw], wl[rr][kw][0], wl[rr][kw][1]);

    f32x4 pf[2][3][2];
#pragma unroll
    for (int s = 0; s < 2; ++s)
#pragma unroll
        for (int kw = 0; kw < 3; ++kw)
            loadf(xg, h0 + 2 + s, wi[kw], vw[kw], pf[s][kw][0], pf[s][kw][1]);

    bf16x8 aw[3][3];
#pragma unroll
    for (int rr = 0; rr < 3; ++rr)
#pragma unroll
        for (int kw = 0; kw < 3; ++kw)
            aw[rr][kw] = cvt8(wl[rr][kw][0], wl[rr][kw][1]);

    const int fbase = wave * 16 + hi * 4;  // filter group-offset this lane stores
    const float4 bv4 = *reinterpret_cast<const float4*>(bias + g * FC + fbase);
    float* const og = out + ((size_t)n * HH * WW) * COUT + g * FC + fbase;

#pragma unroll
    for (int i = 0; i < HCH; ++i) {
        const int h = h0 + i;

        f32x4 acc0 = (f32x4)0.f, acc1 = (f32x4)0.f;
#pragma unroll
        for (int kh = 0; kh < 3; ++kh) {
#pragma unroll
            for (int kw = 0; kw < 3; ++kw) {
                const int t = kh * 3 + kw;
                if (t & 1)
                    acc1 = __builtin_amdgcn_mfma_f32_16x16x32_bf16(bfr[t], aw[kh][kw], acc1, 0, 0, 0);
                else
                    acc0 = __builtin_amdgcn_mfma_f32_16x16x32_bf16(bfr[t], aw[kh][kw], acc0, 0, 0, 0);
            }
        }

        // shift window (consume prefetched row h+2; waits only on its loads)
        if (i + 1 < HCH) {
#pragma unroll
            for (int kw = 0; kw < 3; ++kw) {
                aw[0][kw] = aw[1][kw];
                aw[1][kw] = aw[2][kw];
                aw[2][kw] = cvt8(pf[i & 1][kw][0], pf[i & 1][kw][1]);
            }
        }

        // re-issue freed slot for row h+4 BEFORE the store
        if (i + 4 <= HCH) {
#pragma unroll
            for (int kw = 0; kw < 3; ++kw)
                loadf(xg, h + 4, wi[kw], vw[kw], pf[i & 1][kw][0], pf[i & 1][kw][1]);
        }

        // store: lane writes filters fbase..fbase+3 at (h, w_m) -> 16B contiguous
        if (w_m < WW) {
            const f32x4 a = acc0 + acc1;
            f32x4 o;
            o[0] = a[0] + bv4.x; o[1] = a[1] + bv4.y;
            o[2] = a[2] + bv4.z; o[3] = a[3] + bv4.w;
            f32x4* p = reinterpret_cast<f32x4*>(og + ((size_t)h * WW + w_m) * COUT);
            __builtin_nontemporal_store(o, p);
        }
    }
}

// ---------------- fallback fp32 kernel ----------------
__global__ __launch_bounds__(256, 2)
void groupconv_f32_kernel(const float* __restrict__ x,
                          const float* __restrict__ krn,
                          const float* __restrict__ bias,
                          float* __restrict__ out) {
    const int b  = blockIdx.x;
    const int g  = b % NG;
    const int h  = (b / NG) % HH;
    const int n  = b / (NG * HH);
    const int tid = threadIdx.x;
    const int f   = tid & 63;
    const int wq  = tid >> 6;
    const int wbase = wq * 14;

    float acc[14];
#pragma unroll
    for (int i = 0; i < 14; ++i) acc[i] = 0.f;

    const float* kg = krn + (size_t)g * (9 * PC * FC);

    for (int kh = 0; kh < 3; ++kh) {
        const int hin = h + kh - 1;
        if (hin < 0 || hin >= HH) continue;
        const float* xrow = x + (((size_t)n * HH + hin) * WW) * CIN + g * PC;
        for (int pq = 0; pq < 8; ++pq) {
            float4 xv[16];
#pragma unroll
            for (int t = 0; t < 16; ++t) {
                const int win = wbase + t - 1;
                if (win >= 0 && win < WW)
                    xv[t] = *reinterpret_cast<const float4*>(xrow + (size_t)win * CIN + pq * 4);
                else
                    xv[t] = make_float4(0.f, 0.f, 0.f, 0.f);
            }
#pragma unroll
            for (int kw = 0; kw < 3; ++kw) {
                const float* kp = kg + ((kh * 3 + kw) * PC + pq * 4) * FC + f;
                const float w0 = kp[0 * FC], w1 = kp[1 * FC], w2 = kp[2 * FC], w3 = kp[3 * FC];
#pragma unroll
                for (int i = 0; i < 14; ++i) {
                    const float4 xt = xv[i + kw];
                    acc[i] = fmaf(xt.x, w0, acc[i]);
                    acc[i] = fmaf(xt.y, w1, acc[i]);
                    acc[i] = fmaf(xt.z, w2, acc[i]);
                    acc[i] = fmaf(xt.w, w3, acc[i]);
                }
            }
        }
    }

    const float bv = bias[g * FC + f];
    float* orow = out + (((size_t)n * HH + h) * WW + wbase) * COUT + g * FC + f;
#pragma unroll
    for (int i = 0; i < 14; ++i) orow[(size_t)i * COUT] = acc[i] + bv;
}

// ---------------- launcher ----------------
extern "C" void kernel_launch(void* const* d_in, const int* in_sizes, int n_in,
                              void* d_out, int out_size, void* d_ws, size_t ws_size,
                              hipStream_t stream) {
    const float* x    = (const float*)d_in[0];
    const float* krn  = (const float*)d_in[1];
    const float* bias = (const float*)d_in[2];
    float* out = (float*)d_out;

    const size_t w_elems = (size_t)NG * 9 * FC * PC;
    if (ws_size < w_elems * sizeof(__bf16)) {
        groupconv_f32_kernel<<<NB * HH * NG, 256, 0, stream>>>(x, krn, bias, out);
        return;
    }

    __bf16* wbuf = (__bf16*)d_ws;
    cvt_w_kernel<<<(int)((w_elems + 255) / 256), 256, 0, stream>>>(krn, wbuf);

    const int blocks = NB * NG * 4 * 4;  // 2048
    groupconv_ws2_kernel<<<blocks, 256, 0, stream>>>(x, wbuf, bias, out);
}

// Round 6
// 56.689 us; speedup vs baseline: 10.9812x; 1.8245x over previous
//
#include <hip/hip_runtime.h>

// Grouped conv 3x3 SAME, NHWC fp32 -> LDS-staged bf16 implicit GEMM.
// Block = (n,h,g): stage rows h-1..h+1 (66 w-slots x 32ch) bf16 in LDS
// (XOR-swizzled), weights stationary in regs, 36 MFMA/wave, 1 barrier.
#define NG 8
#define PC 32
#define FC 64
#define HH 56
#define WW 56
#define CIN 256
#define COUT 512
#define NB 16
#define SL 66              // LDS w-slots: w_in = slot-1 in [-1, 64]
#define PLANE (SL * 64)    // bytes per kh plane (66 slots * 32ch * 2B)

typedef __bf16 bf16x8 __attribute__((ext_vector_type(8)));
typedef float f32x4 __attribute__((ext_vector_type(4)));

// kernels [g][kh][kw][p][f] f32 -> [g][tap][f][p] bf16
__global__ void cvt_w_kernel(const float* __restrict__ in,
                             __bf16* __restrict__ outb) {
    int id = blockIdx.x * blockDim.x + threadIdx.x;
    if (id >= NG * 9 * FC * PC) return;
    const int p = id & (PC - 1);
    int rest = id >> 5;
    const int f = rest & (FC - 1);
    rest >>= 6;
    const int t = rest % 9;
    const int g = rest / 9;
    outb[id] = (__bf16)in[(((size_t)(g * 9 + t)) * PC + p) * FC + f];
}

static __device__ __forceinline__ bf16x8 cvt8(f32x4 a, f32x4 b) {
    bf16x8 r;
    r[0] = (__bf16)a[0]; r[1] = (__bf16)a[1]; r[2] = (__bf16)a[2]; r[3] = (__bf16)a[3];
    r[4] = (__bf16)b[0]; r[5] = (__bf16)b[1]; r[6] = (__bf16)b[2]; r[7] = (__bf16)b[3];
    return r;
}

// byte-offset swizzle within a kh plane: XOR slot bits into the ch-quad bits
static __device__ __forceinline__ int swz(int loc) {
    return loc ^ (((loc >> 7) & 3) << 4);
}

__global__ __launch_bounds__(256, 3)
void groupconv_lds_kernel(const float* __restrict__ x,
                          const __bf16* __restrict__ wb,
                          const float* __restrict__ bias,
                          float* __restrict__ out) {
    const int b = blockIdx.x;
    const int g = b & 7;
    const int h = (b >> 3) % HH;
    const int n = b / (8 * HH);

    const int wave = threadIdx.x >> 6;
    const int lane = threadIdx.x & 63;
    const int lo = lane & 15;
    const int hi = lane >> 4;
    const int p0 = hi * 8;

    const int wm = wave >> 1;     // filter half: fm = wm*32
    const int wn = wave & 1;      // w half: wnb = wn*32
    const int fm = wm * 32;
    const int wnb = wn * 32;

    __shared__ __align__(16) unsigned char xsb[3 * PLANE];  // 12672 B

    // ---- stationary weight frags: A-operand (M=filters) ----
    bf16x8 bfr[9][2];
    {
        const __bf16* wgp = wb + ((size_t)g * 9 * FC) * PC;
#pragma unroll
        for (int t = 0; t < 9; ++t)
#pragma unroll
            for (int mi = 0; mi < 2; ++mi)
                bfr[t][mi] = *reinterpret_cast<const bf16x8*>(
                    wgp + ((size_t)t * FC + (fm + mi * 16 + lo)) * PC + p0);
    }

    // ---- cooperative stage: 3 rows x 66 slots x 32 ch -> bf16 LDS ----
    // unit u = (kh, slot, ch-octet): 3*66*4 = 792 units, 16B each
    {
        const int UNITS = 3 * SL * 4;
        for (int u = threadIdx.x; u < UNITS; u += 256) {
            const int hq = u & 3;
            const int s  = (u >> 2) % SL;
            const int kh = (u >> 2) / SL;
            const int w_in = s - 1;
            const int hin  = h + kh - 1;
            f32x4 u0 = (f32x4)0.f, u1 = (f32x4)0.f;
            if ((unsigned)hin < HH && (unsigned)w_in < WW) {
                const float* p = x + (((size_t)n * HH + hin) * WW + w_in) * CIN
                                   + g * PC + hq * 8;
                u0 = *reinterpret_cast<const f32x4*>(p);
                u1 = *reinterpret_cast<const f32x4*>(p + 4);
            }
            const int loc = swz(s * 64 + hq * 16);
            *reinterpret_cast<bf16x8*>(xsb + kh * PLANE + loc) = cvt8(u0, u1);
        }
    }
    __syncthreads();

    // ---- K-loop: 9 taps x 2 nj ds_reads, 36 MFMA ----
    f32x4 acc[2][2];
#pragma unroll
    for (int mi = 0; mi < 2; ++mi)
#pragma unroll
        for (int nj = 0; nj < 2; ++nj) acc[mi][nj] = (f32x4)0.f;

#pragma unroll
    for (int kh = 0; kh < 3; ++kh) {
#pragma unroll
        for (int kw = 0; kw < 3; ++kw) {
            const int t = kh * 3 + kw;
            bf16x8 bx[2];
#pragma unroll
            for (int nj = 0; nj < 2; ++nj) {
                const int s = wnb + nj * 16 + lo + kw;   // slot = w + kw (w_in = w+kw-1)
                const int loc = swz(s * 64 + hi * 16);
                bx[nj] = *reinterpret_cast<const bf16x8*>(xsb + kh * PLANE + loc);
            }
#pragma unroll
            for (int mi = 0; mi < 2; ++mi)
#pragma unroll
                for (int nj = 0; nj < 2; ++nj)
                    acc[mi][nj] = __builtin_amdgcn_mfma_f32_16x16x32_bf16(
                        bfr[t][mi], bx[nj], acc[mi][nj], 0, 0, 0);
        }
    }

    // ---- store: lane holds filters fm+mi*16+hi*4..+3 at w col wnb+nj*16+lo ----
    float* const orow = out + (((size_t)n * HH + h) * WW) * COUT + g * FC;
#pragma unroll
    for (int mi = 0; mi < 2; ++mi) {
        const int f0 = fm + mi * 16 + hi * 4;
        const float4 bv = *reinterpret_cast<const float4*>(bias + g * FC + f0);
#pragma unroll
        for (int nj = 0; nj < 2; ++nj) {
            const int w = wnb + nj * 16 + lo;
            if (w < WW) {
                f32x4 o = acc[mi][nj];
                o[0] += bv.x; o[1] += bv.y; o[2] += bv.z; o[3] += bv.w;
                *reinterpret_cast<f32x4*>(orow + (size_t)w * COUT + f0) = o;
            }
        }
    }
}

// ---------------- fallback fp32 kernel ----------------
__global__ __launch_bounds__(256, 2)
void groupconv_f32_kernel(const float* __restrict__ x,
                          const float* __restrict__ krn,
                          const float* __restrict__ bias,
                          float* __restrict__ out) {
    const int b  = blockIdx.x;
    const int g  = b % NG;
    const int h  = (b / NG) % HH;
    const int n  = b / (NG * HH);
    const int tid = threadIdx.x;
    const int f   = tid & 63;
    const int wq  = tid >> 6;
    const int wbase = wq * 14;

    float acc[14];
#pragma unroll
    for (int i = 0; i < 14; ++i) acc[i] = 0.f;

    const float* kg = krn + (size_t)g * (9 * PC * FC);

    for (int kh = 0; kh < 3; ++kh) {
        const int hin = h + kh - 1;
        if (hin < 0 || hin >= HH) continue;
        const float* xrow = x + (((size_t)n * HH + hin) * WW) * CIN + g * PC;
        for (int pq = 0; pq < 8; ++pq) {
            float4 xv[16];
#pragma unroll
            for (int t = 0; t < 16; ++t) {
                const int win = wbase + t - 1;
                if (win >= 0 && win < WW)
                    xv[t] = *reinterpret_cast<const float4*>(xrow + (size_t)win * CIN + pq * 4);
                else
                    xv[t] = make_float4(0.f, 0.f, 0.f, 0.f);
            }
#pragma unroll
            for (int kw = 0; kw < 3; ++kw) {
                const float* kp = kg + ((kh * 3 + kw) * PC + pq * 4) * FC + f;
                const float w0 = kp[0 * FC], w1 = kp[1 * FC], w2 = kp[2 * FC], w3 = kp[3 * FC];
#pragma unroll
                for (int i = 0; i < 14; ++i) {
                    const float4 xt = xv[i + kw];
                    acc[i] = fmaf(xt.x, w0, acc[i]);
                    acc[i] = fmaf(xt.y, w1, acc[i]);
                    acc[i] = fmaf(xt.z, w2, acc[i]);
                    acc[i] = fmaf(xt.w, w3, acc[i]);
                }
            }
        }
    }

    const float bv = bias[g * FC + f];
    float* orow = out + (((size_t)n * HH + h) * WW + wbase) * COUT + g * FC + f;
#pragma unroll
    for (int i = 0; i < 14; ++i) orow[(size_t)i * COUT] = acc[i] + bv;
}

// ---------------- launcher ----------------
extern "C" void kernel_launch(void* const* d_in, const int* in_sizes, int n_in,
                              void* d_out, int out_size, void* d_ws, size_t ws_size,
                              hipStream_t stream) {
    const float* x    = (const float*)d_in[0];
    const float* krn  = (const float*)d_in[1];
    const float* bias = (const float*)d_in[2];
    float* out = (float*)d_out;

    const size_t w_elems = (size_t)NG * 9 * FC * PC;
    if (ws_size < w_elems * sizeof(__bf16)) {
        groupconv_f32_kernel<<<NB * HH * NG, 256, 0, stream>>>(x, krn, bias, out);
        return;
    }

    __bf16* wbuf = (__bf16*)d_ws;
    cvt_w_kernel<<<(int)((w_elems + 255) / 256), 256, 0, stream>>>(krn, wbuf);

    const int blocks = NB * HH * NG;  // 7168
    groupconv_lds_kernel<<<blocks, 256, 0, stream>>>(x, wbuf, bias, out);
}

// Round 7
// 49.939 us; speedup vs baseline: 12.4654x; 1.1352x over previous
//
#include <hip/hip_runtime.h>

// Grouped conv 3x3 SAME, NHWC fp32 -> bf16 MFMA, LDS 5-plane ring h-walk.
// Block=(n,g,hchunk of 7): stage rows into a 5-plane LDS ring (1 barrier/iter,
// write->barrier->read; 5 planes needed for race-freedom), reg-prefetch one
// row ahead (T14), weights stationary, NT output stores.
#define NG 8
#define PC 32
#define FC 64
#define HH 56
#define WW 56
#define CIN 256
#define COUT 512
#define NB 16
#define SL 66              // w slots: w_in = slot-1 in [-1,64]
#define PLANE (SL * 64)    // 4224 B per plane (66 slots * 32ch * 2B)
#define NPL 5              // ring planes
#define HCH 7              // h rows per block

typedef __bf16 bf16x8 __attribute__((ext_vector_type(8)));
typedef float f32x4 __attribute__((ext_vector_type(4)));

// kernels [g][kh][kw][p][f] f32 -> [g][tap][f][p] bf16
__global__ void cvt_w_kernel(const float* __restrict__ in,
                             __bf16* __restrict__ outb) {
    int id = blockIdx.x * blockDim.x + threadIdx.x;
    if (id >= NG * 9 * FC * PC) return;
    const int p = id & (PC - 1);
    int rest = id >> 5;
    const int f = rest & (FC - 1);
    rest >>= 6;
    const int t = rest % 9;
    const int g = rest / 9;
    outb[id] = (__bf16)in[(((size_t)(g * 9 + t)) * PC + p) * FC + f];
}

static __device__ __forceinline__ bf16x8 cvt8(f32x4 a, f32x4 b) {
    bf16x8 r;
    r[0] = (__bf16)a[0]; r[1] = (__bf16)a[1]; r[2] = (__bf16)a[2]; r[3] = (__bf16)a[3];
    r[4] = (__bf16)b[0]; r[5] = (__bf16)b[1]; r[6] = (__bf16)b[2]; r[7] = (__bf16)b[3];
    return r;
}

static __device__ __forceinline__ int swz(int loc) {
    return loc ^ (((loc >> 7) & 3) << 4);
}

__global__ __launch_bounds__(256, 4)
void groupconv_ring_kernel(const float* __restrict__ x,
                           const __bf16* __restrict__ wb,
                           const float* __restrict__ bias,
                           float* __restrict__ out) {
    const int b   = blockIdx.x;
    const int g   = b & 7;
    const int hcb = (b >> 3) & 7;
    const int n   = b >> 6;
    const int h0  = hcb * HCH;

    const int tid  = threadIdx.x;
    const int wave = tid >> 6;
    const int lane = tid & 63;
    const int lo = lane & 15;
    const int hi = lane >> 4;
    const int p0 = hi * 8;
    const int fm  = (wave >> 1) * 32;   // filter half
    const int wnb = (wave & 1) * 32;    // w half

    __shared__ __align__(16) unsigned char xsb[NPL * PLANE];  // 21120 B

    // ---- stationary weight frags (A-operand: M=filters) ----
    bf16x8 bfr[9][2];
    {
        const __bf16* wgp = wb + ((size_t)g * 9 * FC) * PC;
#pragma unroll
        for (int t = 0; t < 9; ++t)
#pragma unroll
            for (int mi = 0; mi < 2; ++mi)
                bfr[t][mi] = *reinterpret_cast<const bf16x8*>(
                    wgp + ((size_t)t * FC + (fm + mi * 16 + lo)) * PC + p0);
    }

    // ---- zero-fill constant-zero slots (57..65) of all planes, once ----
    if (tid < 180) {
        const int q  = tid & 3;
        const int sq = tid >> 2;        // 0..44
        const int pl = sq / 9;
        const int s  = 57 + (sq % 9);
        *reinterpret_cast<bf16x8*>(xsb + pl * PLANE + swz(s * 64 + q * 16)) =
            (bf16x8)(__bf16)0.f;
    }

    // ---- stage mapping: thread -> (slot, ch-octet), slots 0..56 active ----
    const int sq_q = tid & 3;
    const int sq_s = tid >> 2;          // 0..63
    const bool st_act = sq_s < 57;
    const int w_in = sq_s - 1;
    const bool w_ok = st_act && ((unsigned)w_in < WW);
    const float* xq = x + ((size_t)n * HH * WW) * CIN + g * PC + sq_q * 8;
    const int wloc = swz(sq_s * 64 + sq_q * 16);

    // ---- prologue: rows h0-1..h0+1 -> planes 0..2 ----
    f32x4 pa[3], pb[3];
#pragma unroll
    for (int rr = 0; rr < 3; ++rr) {
        const int r = h0 - 1 + rr;
        pa[rr] = (f32x4)0.f; pb[rr] = (f32x4)0.f;
        if (w_ok && (unsigned)r < HH) {
            const float* p = xq + ((size_t)r * WW + w_in) * CIN;
            pa[rr] = *reinterpret_cast<const f32x4*>(p);
            pb[rr] = *reinterpret_cast<const f32x4*>(p + 4);
        }
    }
#pragma unroll
    for (int rr = 0; rr < 3; ++rr)
        if (st_act)
            *reinterpret_cast<bf16x8*>(xsb + rr * PLANE + wloc) = cvt8(pa[rr], pb[rr]);

    // reg-prefetch row h0+2
    f32x4 sa = (f32x4)0.f, sb = (f32x4)0.f;
    {
        const int r = h0 + 2;
        if (w_ok && (unsigned)r < HH) {
            const float* p = xq + ((size_t)r * WW + w_in) * CIN;
            sa = *reinterpret_cast<const f32x4*>(p);
            sb = *reinterpret_cast<const f32x4*>(p + 4);
        }
    }

    float4 bvv[2];
#pragma unroll
    for (int mi = 0; mi < 2; ++mi)
        bvv[mi] = *reinterpret_cast<const float4*>(bias + g * FC + fm + mi * 16 + hi * 4);

    float* const outg = out + ((size_t)n * HH * WW) * COUT + g * FC;

#pragma unroll
    for (int i = 0; i < HCH; ++i) {
        const int h = h0 + i;

        // write staged row h+2 -> plane (i+3)%5  (before barrier)
        if (st_act)
            *reinterpret_cast<bf16x8*>(xsb + ((i + 3) % NPL) * PLANE + wloc) = cvt8(sa, sb);

        // issue loads for row h+3 (consumed next iter)
        if (i + 1 < HCH) {
            const int r = h + 3;
            sa = (f32x4)0.f; sb = (f32x4)0.f;
            if (w_ok && (unsigned)r < HH) {
                const float* p = xq + ((size_t)r * WW + w_in) * CIN;
                sa = *reinterpret_cast<const f32x4*>(p);
                sb = *reinterpret_cast<const f32x4*>(p + 4);
            }
        }

        __syncthreads();

        // compute row h: planes (i+kh)%5, 18 ds_read + 36 MFMA
        f32x4 acc[2][2];
#pragma unroll
        for (int mi = 0; mi < 2; ++mi)
#pragma unroll
            for (int nj = 0; nj < 2; ++nj) acc[mi][nj] = (f32x4)0.f;

#pragma unroll
        for (int kh = 0; kh < 3; ++kh) {
            const unsigned char* plb = xsb + ((i + kh) % NPL) * PLANE;
#pragma unroll
            for (int kw = 0; kw < 3; ++kw) {
                const int t = kh * 3 + kw;
                bf16x8 bx[2];
#pragma unroll
                for (int nj = 0; nj < 2; ++nj) {
                    const int s = wnb + nj * 16 + lo + kw;
                    bx[nj] = *reinterpret_cast<const bf16x8*>(plb + swz(s * 64 + hi * 16));
                }
#pragma unroll
                for (int mi = 0; mi < 2; ++mi)
#pragma unroll
                    for (int nj = 0; nj < 2; ++nj)
                        acc[mi][nj] = __builtin_amdgcn_mfma_f32_16x16x32_bf16(
                            bfr[t][mi], bx[nj], acc[mi][nj], 0, 0, 0);
            }
        }

        // store row h: lane -> filters f0..f0+3 at col w (16B NT store)
        float* const orow = outg + ((size_t)h * WW) * COUT;
#pragma unroll
        for (int mi = 0; mi < 2; ++mi) {
            const int f0 = fm + mi * 16 + hi * 4;
#pragma unroll
            for (int nj = 0; nj < 2; ++nj) {
                const int w = wnb + nj * 16 + lo;
                if (w < WW) {
                    f32x4 o = acc[mi][nj];
                    o[0] += bvv[mi].x; o[1] += bvv[mi].y;
                    o[2] += bvv[mi].z; o[3] += bvv[mi].w;
                    __builtin_nontemporal_store(
                        o, reinterpret_cast<f32x4*>(orow + (size_t)w * COUT + f0));
                }
            }
        }
    }
}

// ---------------- fallback fp32 kernel ----------------
__global__ __launch_bounds__(256, 2)
void groupconv_f32_kernel(const float* __restrict__ x,
                          const float* __restrict__ krn,
                          const float* __restrict__ bias,
                          float* __restrict__ out) {
    const int b  = blockIdx.x;
    const int g  = b % NG;
    const int h  = (b / NG) % HH;
    const int n  = b / (NG * HH);
    const int tid = threadIdx.x;
    const int f   = tid & 63;
    const int wq  = tid >> 6;
    const int wbase = wq * 14;

    float acc[14];
#pragma unroll
    for (int i = 0; i < 14; ++i) acc[i] = 0.f;

    const float* kg = krn + (size_t)g * (9 * PC * FC);

    for (int kh = 0; kh < 3; ++kh) {
        const int hin = h + kh - 1;
        if (hin < 0 || hin >= HH) continue;
        const float* xrow = x + (((size_t)n * HH + hin) * WW) * CIN + g * PC;
        for (int pq = 0; pq < 8; ++pq) {
            float4 xv[16];
#pragma unroll
            for (int t = 0; t < 16; ++t) {
                const int win = wbase + t - 1;
                if (win >= 0 && win < WW)
                    xv[t] = *reinterpret_cast<const float4*>(xrow + (size_t)win * CIN + pq * 4);
                else
                    xv[t] = make_float4(0.f, 0.f, 0.f, 0.f);
            }
#pragma unroll
            for (int kw = 0; kw < 3; ++kw) {
                const float* kp = kg + ((kh * 3 + kw) * PC + pq * 4) * FC + f;
                const float w0 = kp[0 * FC], w1 = kp[1 * FC], w2 = kp[2 * FC], w3 = kp[3 * FC];
#pragma unroll
                for (int i = 0; i < 14; ++i) {
                    const float4 xt = xv[i + kw];
                    acc[i] = fmaf(xt.x, w0, acc[i]);
                    acc[i] = fmaf(xt.y, w1, acc[i]);
                    acc[i] = fmaf(xt.z, w2, acc[i]);
                    acc[i] = fmaf(xt.w, w3, acc[i]);
                }
            }
        }
    }

    const float bv = bias[g * FC + f];
    float* orow = out + (((size_t)n * HH + h) * WW + wbase) * COUT + g * FC + f;
#pragma unroll
    for (int i = 0; i < 14; ++i) orow[(size_t)i * COUT] = acc[i] + bv;
}

// ---------------- launcher ----------------
extern "C" void kernel_launch(void* const* d_in, const int* in_sizes, int n_in,
                              void* d_out, int out_size, void* d_ws, size_t ws_size,
                              hipStream_t stream) {
    const float* x    = (const float*)d_in[0];
    const float* krn  = (const float*)d_in[1];
    const float* bias = (const float*)d_in[2];
    float* out = (float*)d_out;

    const size_t w_elems = (size_t)NG * 9 * FC * PC;
    if (ws_size < w_elems * sizeof(__bf16)) {
        groupconv_f32_kernel<<<NB * HH * NG, 256, 0, stream>>>(x, krn, bias, out);
        return;
    }

    __bf16* wbuf = (__bf16*)d_ws;
    cvt_w_kernel<<<(int)((w_elems + 255) / 256), 256, 0, stream>>>(krn, wbuf);

    const int blocks = NB * 8 * NG;  // n * hchunks * g = 1024
    groupconv_ring_kernel<<<blocks, 256, 0, stream>>>(x, wbuf, bias, out);
}